// Round 4
// baseline (245.691 us; speedup 1.0000x reference)
//
#include <hip/hip_runtime.h>

#define N_NODES 50000
#define N_EDGES 300000
#define N_TOT   350000   // edges + self-loops
#define D       256
#define MPAD    50048    // N_NODES padded to multiple of 64 for layer tiles
#define SCAN_B  196      // ceil(50000/256)
#define BLKM    64
#define LGRID   (MPAD / BLKM)   // 782

typedef __attribute__((ext_vector_type(8))) short bf16x8;
typedef __attribute__((ext_vector_type(4))) float f32x4;
typedef __attribute__((ext_vector_type(8))) unsigned short u16x8;
typedef __attribute__((ext_vector_type(4))) unsigned short u16x4;

__device__ __forceinline__ float bf2f(unsigned short b) {
    union { unsigned u; float f; } v; v.u = ((unsigned)b) << 16; return v.f;
}
__device__ __forceinline__ unsigned short f2bf(float f) {
    union { float f; unsigned u; } v; v.f = f;
    unsigned u = v.u;
    unsigned r = (u + 0x7FFFu + ((u >> 16) & 1u)) >> 16;   // round-nearest-even
    return (unsigned short)r;
}
__device__ __forceinline__ void g2lds16(const unsigned short* g, unsigned short* l) {
    __builtin_amdgcn_global_load_lds(
        (const __attribute__((address_space(1))) void*)g,
        (__attribute__((address_space(3))) void*)l, 16, 0, 0);
}

// ---- k1: hist + W-transpose + embed, all independent, grid = MPAD/8 = 6256 ----
__global__ __launch_bounds__(256) void k1_kernel(
        const float* __restrict__ x, const int* __restrict__ ei,
        const float* __restrict__ We, const float* __restrict__ be,
        const float* __restrict__ W1, const float* __restrict__ W2,
        int* __restrict__ cnt,
        unsigned short* __restrict__ Wt1, unsigned short* __restrict__ Wt2,
        unsigned short* __restrict__ hA) {
    int t = threadIdx.x, b = blockIdx.x;
    int tid = b * 256 + t;

    // histogram over dst (cnt pre-zeroed by memset)
    if (tid < N_TOT) {
        int dst = (tid < N_EDGES) ? ei[N_EDGES + tid] : (tid - N_EDGES);
        atomicAdd(&cnt[dst], 1);
    }
    // transpose + cast weights (first 512 blocks, 1 elem/thread)
    if (tid < 2 * D * D) {
        int wsel = tid >> 16, rem = tid & 65535;
        int tt = rem >> 8, bb = rem & 255;             // coalesced over bb
        const float* W = wsel ? W2 : W1;
        unsigned short* Wt = wsel ? Wt2 : Wt1;
        Wt[bb * D + tt] = f2bf(W[tt * D + bb]);
    }
    // embed: block b -> nodes b*8 .. b*8+7 (pad rows get 0)
    float w[11];
    #pragma unroll
    for (int k = 0; k < 11; ++k) w[k] = We[k * D + t];
    float bb = be[t];
    #pragma unroll
    for (int ni = 0; ni < 8; ++ni) {
        int node = b * 8 + ni;
        float acc = 0.f;
        if (node < N_NODES) {
            acc = bb;
            #pragma unroll
            for (int k = 0; k < 11; ++k) acc += x[node * 11 + k] * w[k];
            acc = fmaxf(acc, 0.f);
        }
        hA[(size_t)node * D + t] = f2bf(acc);
    }
}

// ---- k2: standalone scan (decoupled single-pass, 196 blocks) ----
__global__ __launch_bounds__(256) void k2_kernel(const int* __restrict__ cnt,
                                                 float* __restrict__ dis,
                                                 int* __restrict__ locs,
                                                 int* __restrict__ bsum,
                                                 int* __restrict__ done) {
    __shared__ int ws[4];
    __shared__ int amLast;
    int t = threadIdx.x;
    int lane = t & 63, wv4 = t >> 6;
    int i = blockIdx.x * 256 + t;
    int v = (i < N_NODES) ? cnt[i] : 0;
    if (i < N_NODES) dis[i] = rsqrtf((float)v);    // deg >= 1 (self-loop)
    int s = v;
    #pragma unroll
    for (int d = 1; d < 64; d <<= 1) {
        int u = __shfl_up(s, d, 64);
        if (lane >= d) s += u;
    }
    if (lane == 63) ws[wv4] = s;
    __syncthreads();
    int off = 0;
    #pragma unroll
    for (int k = 0; k < 4; ++k) if (k < wv4) off += ws[k];
    s += off;
    if (i < N_NODES) locs[i] = s;                  // inclusive local scan
    if (t == 255) {
        bsum[blockIdx.x] = s;
        __threadfence();
        amLast = (atomicAdd(done, 1) == SCAN_B - 1);
    }
    __syncthreads();
    if (amLast) {
        __threadfence();
        int vv = 0;
        if (t < SCAN_B)
            vv = __hip_atomic_load(&bsum[t], __ATOMIC_RELAXED, __HIP_MEMORY_SCOPE_AGENT);
        int ss = vv;
        #pragma unroll
        for (int d = 1; d < 64; d <<= 1) {
            int u = __shfl_up(ss, d, 64);
            if (lane >= d) ss += u;
        }
        __syncthreads();                           // ws reuse
        if (lane == 63) ws[wv4] = ss;
        __syncthreads();
        int off2 = 0;
        #pragma unroll
        for (int k = 0; k < 4; ++k) if (k < wv4) off2 += ws[k];
        ss += off2;
        if (t < SCAN_B) bsum[t] = ss - vv;         // exclusive block offsets
    }
}

// ---- k3: rowptr materialization + CSR fill (packed src+norm, one 8B store) ----
__global__ __launch_bounds__(256) void k3_kernel(const int* __restrict__ ei,
                          const int* __restrict__ locs,
                          const int* __restrict__ bsum, const float* __restrict__ dis,
                          int* __restrict__ fc, int* __restrict__ rowptr,
                          int2* __restrict__ epk) {
    int tid = blockIdx.x * 256 + threadIdx.x;
    if (tid == 0) rowptr[0] = 0;
    if (tid < N_NODES)
        rowptr[tid + 1] = locs[tid] + bsum[tid >> 8];
    if (tid < N_TOT) {
        int src, dst;
        if (tid < N_EDGES) { src = ei[tid]; dst = ei[N_EDGES + tid]; }
        else               { src = dst = tid - N_EDGES; }
        int base = bsum[dst >> 8] + ((dst & 255) ? locs[dst - 1] : 0);
        int pos = base + atomicAdd(&fc[dst], 1);
        epk[pos] = make_int2(src, __float_as_int(dis[src] * dis[dst]));
    }
}

// ---- fused layer: out = act( Agg(hw) * Wt^T + bias )  (aggregate-FIRST form,
// valid by linearity of Agg). Per block: 64 nodes; each half-wave (32 lanes x
// 8 dims = 256) aggregates 8 nodes sequentially, 8 edges in flight, writing
// the bf16 A-tile into LDS (XOR chunk-swizzle (chunk^row)&7 -> b128 bank
// floor). Then full-N=256 GEMM: B (Wt) staged 16KB per K-step via
// global_load_lds with source-preswizzle c^((n>>1)&3) (linear LDS dest).
// Swapped-operand MFMA epilogue fuses bias (+relu for mode=1). ----
__global__ __launch_bounds__(256, 3) void layer_kernel(
        const unsigned short* __restrict__ hw,    // gather table [N][D] bf16
        const int* __restrict__ rowptr,
        const int2* __restrict__ epk,
        const unsigned short* __restrict__ Bt,    // Wt [n][k] bf16
        const float* __restrict__ bias,
        unsigned short* __restrict__ out_bf,
        float* __restrict__ out_f32,
        int mode) {                               // 1 = relu->bf16, 0 = f32
    __shared__ unsigned short lA[BLKM * D];       // 32 KB
    __shared__ unsigned short lB[D * 32];         // 16 KB
    int t = threadIdx.x;
    int bid = blockIdx.x;
    int wid = t >> 6, lane = t & 63;
    int h = lane >> 5, hl = lane & 31;
    int hw8 = wid * 2 + h;                        // half-wave id 0..7
    int m0 = bid * BLKM;

    // prologue: stage B K-step 0 (overlaps with agg phase)
    #pragma unroll
    for (int j2 = 0; j2 < 4; ++j2) {
        int idx = j2 * 256 + t;
        int n = idx >> 2, c = idx & 3;
        int cs = c ^ ((n >> 1) & 3);
        g2lds16(Bt + (size_t)n * D + cs * 8, lB + idx * 8);
    }

    // ---- agg phase: 8 nodes per half-wave ----
    for (int j = 0; j < 8; ++j) {
        int nn = hw8 * 8 + j;
        int node = m0 + nn;
        float acc[8] = {};
        if (node < N_NODES) {
            int s0 = rowptr[node], s1 = rowptr[node + 1];
            for (int base = s0; base < s1; base += 8) {
                int idx = base + (hl & 7);
                int srcl = 0; float nml = 0.f;
                if (idx < s1) {
                    int2 ep = epk[idx];
                    srcl = ep.x; nml = __int_as_float(ep.y);
                }
                int se[8]; float ne[8]; u16x8 rw[8];
                #pragma unroll
                for (int e = 0; e < 8; ++e) {
                    se[e] = __shfl(srcl, h * 32 + e, 64);
                    ne[e] = __shfl(nml,  h * 32 + e, 64);
                }
                #pragma unroll
                for (int e = 0; e < 8; ++e)
                    rw[e] = *(const u16x8*)(hw + (size_t)se[e] * D + hl * 8);
                #pragma unroll
                for (int e = 0; e < 8; ++e)
                    #pragma unroll
                    for (int k = 0; k < 8; ++k) acc[k] += ne[e] * bf2f(rw[e][k]);
            }
        }
        u16x8 o;
        #pragma unroll
        for (int k = 0; k < 8; ++k) o[k] = f2bf(acc[k]);
        int chunk = (hl & ~7) | ((hl ^ nn) & 7);      // A chunk swizzle (write)
        *(u16x8*)(lA + nn * D + chunk * 8) = o;
    }

    __syncthreads();   // A-tile ready + B step-0 staged (vmcnt drained)

    // ---- GEMM phase: each wave computes 64(M) x 64(N-quarter) ----
    int q = lane >> 4, r = lane & 15;
    int noff = wid * 64;
    f32x4 acc4[4][4] = {};
    for (int st = 0; st < 8; ++st) {
        bf16x8 af[4], bfr[4];
        #pragma unroll
        for (int mt = 0; mt < 4; ++mt) {
            int row = mt * 16 + r;
            int ch = st * 4 + q;
            int chs = (ch & ~7) | ((ch ^ row) & 7);   // A chunk swizzle (read)
            af[mt] = *(const bf16x8*)(lA + row * D + chs * 8);
        }
        #pragma unroll
        for (int nt = 0; nt < 4; ++nt) {
            int n = noff + nt * 16 + r;
            int cb = q ^ ((n >> 1) & 3);              // B chunk swizzle (read)
            bfr[nt] = *(const bf16x8*)(lB + n * 32 + cb * 8);
        }
        #pragma unroll
        for (int mt = 0; mt < 4; ++mt)
            #pragma unroll
            for (int nt = 0; nt < 4; ++nt)
                acc4[mt][nt] = __builtin_amdgcn_mfma_f32_16x16x32_bf16(
                    bfr[nt], af[mt], acc4[mt][nt], 0, 0, 0);
        if (st < 7) {
            __syncthreads();                           // all reads of lB done
            int kk = (st + 1) * 32;
            #pragma unroll
            for (int j2 = 0; j2 < 4; ++j2) {
                int idx = j2 * 256 + t;
                int n = idx >> 2, c = idx & 3;
                int cs = c ^ ((n >> 1) & 3);
                g2lds16(Bt + (size_t)n * D + kk + cs * 8, lB + idx * 8);
            }
            __syncthreads();                           // staging visible
        }
    }

    // ---- epilogue: bias (+relu), swapped-operand layout: row=r, col=q*4+i ----
    #pragma unroll
    for (int mt = 0; mt < 4; ++mt) {
        int mrow = m0 + mt * 16 + r;
        if (mrow >= N_NODES) continue;
        #pragma unroll
        for (int nt = 0; nt < 4; ++nt) {
            int col = noff + nt * 16 + (q << 2);
            float4 bv = *(const float4*)(bias + col);
            float v[4] = { acc4[mt][nt][0] + bv.x, acc4[mt][nt][1] + bv.y,
                           acc4[mt][nt][2] + bv.z, acc4[mt][nt][3] + bv.w };
            if (mode) {
                u16x4 o;
                #pragma unroll
                for (int i = 0; i < 4; ++i) o[i] = f2bf(fmaxf(v[i], 0.f));
                *(u16x4*)(out_bf + (size_t)mrow * D + col) = o;
            } else {
                float4 o = { v[0], v[1], v[2], v[3] };
                *(float4*)(out_f32 + (size_t)mrow * D + col) = o;
            }
        }
    }
}

extern "C" void kernel_launch(void* const* d_in, const int* in_sizes, int n_in,
                              void* d_out, int out_size, void* d_ws, size_t ws_size,
                              hipStream_t stream) {
    const float* x  = (const float*)d_in[0];
    const int*   ei = (const int*)d_in[1];
    const float* We = (const float*)d_in[2];
    const float* be = (const float*)d_in[3];
    const float* W1 = (const float*)d_in[4];
    const float* b1 = (const float*)d_in[5];
    const float* W2 = (const float*)d_in[6];
    const float* b2 = (const float*)d_in[7];
    float* out = (float*)d_out;

    char* w = (char*)d_ws;
    auto alloc = [&](size_t bytes) {
        char* p = w;
        w += (bytes + 255) & ~(size_t)255;
        return p;
    };
    // cnt, fc, done contiguous -> single memset covers all three
    int*            cnt    = (int*)alloc((size_t)N_NODES * 4);
    int*            fc     = (int*)alloc((size_t)N_NODES * 4);
    int*            done   = (int*)alloc(4);
    size_t zero_span = (size_t)((char*)(done + 64) - (char*)cnt);
    int*            rowptr = (int*)alloc((size_t)(N_NODES + 1) * 4);
    int*            locs   = (int*)alloc((size_t)N_NODES * 4);
    int*            bsum   = (int*)alloc((size_t)SCAN_B * 4);
    float*          dis    = (float*)alloc((size_t)N_NODES * 4);
    int2*           epk    = (int2*)alloc((size_t)N_TOT * 8);
    unsigned short* Wt1    = (unsigned short*)alloc((size_t)D * D * 2);
    unsigned short* Wt2    = (unsigned short*)alloc((size_t)D * D * 2);
    unsigned short* hA     = (unsigned short*)alloc((size_t)MPAD * D * 2);
    unsigned short* h1     = (unsigned short*)alloc((size_t)MPAD * D * 2);

    hipMemsetAsync(cnt, 0, zero_span, stream);
    k1_kernel<<<MPAD / 8, 256, 0, stream>>>(x, ei, We, be, W1, W2, cnt, Wt1, Wt2, hA);
    k2_kernel<<<SCAN_B, 256, 0, stream>>>(cnt, dis, locs, bsum, done);
    k3_kernel<<<(N_TOT + 255) / 256, 256, 0, stream>>>(ei, locs, bsum, dis, fc,
                                                       rowptr, epk);
    // layer 1: h1 = relu( Agg(hA) * W1 + b1 )
    layer_kernel<<<LGRID, 256, 0, stream>>>(hA, rowptr, epk, Wt1, b1,
                                            h1, nullptr, 1);
    // layer 2: out = Agg(h1) * W2 + b2
    layer_kernel<<<LGRID, 256, 0, stream>>>(h1, rowptr, epk, Wt2, b2,
                                            nullptr, out, 0);
}

// Round 5
// 235.397 us; speedup vs baseline: 1.0437x; 1.0437x over previous
//
#include <hip/hip_runtime.h>

#define N_NODES 50000
#define N_EDGES 300000
#define N_TOT   350000   // edges + self-loops
#define D       256
#define MPAD    50048    // N_NODES padded to multiple of 64 for layer tiles
#define SCAN_B  196      // ceil(50000/256)
#define BLKM    64
#define LGRID   (MPAD / BLKM)   // 782
#define EMAX    896      // LDS edge-slice capacity (mean 448, sigma ~20 -> 22 sigma)

typedef __attribute__((ext_vector_type(8))) short bf16x8;
typedef __attribute__((ext_vector_type(4))) float f32x4;
typedef __attribute__((ext_vector_type(8))) unsigned short u16x8;
typedef __attribute__((ext_vector_type(4))) unsigned short u16x4;

__device__ __forceinline__ float bf2f(unsigned short b) {
    union { unsigned u; float f; } v; v.u = ((unsigned)b) << 16; return v.f;
}
__device__ __forceinline__ unsigned short f2bf(float f) {
    union { float f; unsigned u; } v; v.f = f;
    unsigned u = v.u;
    unsigned r = (u + 0x7FFFu + ((u >> 16) & 1u)) >> 16;   // round-nearest-even
    return (unsigned short)r;
}

// ---- k1: hist + W-transpose + embed, all independent, grid = MPAD/8 = 6256 ----
__global__ __launch_bounds__(256) void k1_kernel(
        const float* __restrict__ x, const int* __restrict__ ei,
        const float* __restrict__ We, const float* __restrict__ be,
        const float* __restrict__ W1, const float* __restrict__ W2,
        int* __restrict__ cnt,
        unsigned short* __restrict__ Wt1, unsigned short* __restrict__ Wt2,
        unsigned short* __restrict__ hA) {
    int t = threadIdx.x, b = blockIdx.x;
    int tid = b * 256 + t;

    // histogram over dst (cnt pre-zeroed by memset)
    if (tid < N_TOT) {
        int dst = (tid < N_EDGES) ? ei[N_EDGES + tid] : (tid - N_EDGES);
        atomicAdd(&cnt[dst], 1);
    }
    // transpose + cast weights (first 512 blocks, 1 elem/thread)
    if (tid < 2 * D * D) {
        int wsel = tid >> 16, rem = tid & 65535;
        int tt = rem >> 8, bb = rem & 255;             // coalesced over bb
        const float* W = wsel ? W2 : W1;
        unsigned short* Wt = wsel ? Wt2 : Wt1;
        Wt[bb * D + tt] = f2bf(W[tt * D + bb]);
    }
    // embed: block b -> nodes b*8 .. b*8+7 (pad rows get 0)
    float w[11];
    #pragma unroll
    for (int k = 0; k < 11; ++k) w[k] = We[k * D + t];
    float bb = be[t];
    #pragma unroll
    for (int ni = 0; ni < 8; ++ni) {
        int node = b * 8 + ni;
        float acc = 0.f;
        if (node < N_NODES) {
            acc = bb;
            #pragma unroll
            for (int k = 0; k < 11; ++k) acc += x[node * 11 + k] * w[k];
            acc = fmaxf(acc, 0.f);
        }
        hA[(size_t)node * D + t] = f2bf(acc);
    }
}

// ---- k2: standalone scan (decoupled single-pass, 196 blocks) ----
__global__ __launch_bounds__(256) void k2_kernel(const int* __restrict__ cnt,
                                                 float* __restrict__ dis,
                                                 int* __restrict__ locs,
                                                 int* __restrict__ bsum,
                                                 int* __restrict__ done) {
    __shared__ int ws[4];
    __shared__ int amLast;
    int t = threadIdx.x;
    int lane = t & 63, wv4 = t >> 6;
    int i = blockIdx.x * 256 + t;
    int v = (i < N_NODES) ? cnt[i] : 0;
    if (i < N_NODES) dis[i] = rsqrtf((float)v);    // deg >= 1 (self-loop)
    int s = v;
    #pragma unroll
    for (int d = 1; d < 64; d <<= 1) {
        int u = __shfl_up(s, d, 64);
        if (lane >= d) s += u;
    }
    if (lane == 63) ws[wv4] = s;
    __syncthreads();
    int off = 0;
    #pragma unroll
    for (int k = 0; k < 4; ++k) if (k < wv4) off += ws[k];
    s += off;
    if (i < N_NODES) locs[i] = s;                  // inclusive local scan
    if (t == 255) {
        bsum[blockIdx.x] = s;
        __threadfence();
        amLast = (atomicAdd(done, 1) == SCAN_B - 1);
    }
    __syncthreads();
    if (amLast) {
        __threadfence();
        int vv = 0;
        if (t < SCAN_B)
            vv = __hip_atomic_load(&bsum[t], __ATOMIC_RELAXED, __HIP_MEMORY_SCOPE_AGENT);
        int ss = vv;
        #pragma unroll
        for (int d = 1; d < 64; d <<= 1) {
            int u = __shfl_up(ss, d, 64);
            if (lane >= d) ss += u;
        }
        __syncthreads();                           // ws reuse
        if (lane == 63) ws[wv4] = ss;
        __syncthreads();
        int off2 = 0;
        #pragma unroll
        for (int k = 0; k < 4; ++k) if (k < wv4) off2 += ws[k];
        ss += off2;
        if (t < SCAN_B) bsum[t] = ss - vv;         // exclusive block offsets
    }
}

// ---- k3: rowptr materialization + CSR fill (packed src+norm, one 8B store) ----
__global__ __launch_bounds__(256) void k3_kernel(const int* __restrict__ ei,
                          const int* __restrict__ locs,
                          const int* __restrict__ bsum, const float* __restrict__ dis,
                          int* __restrict__ fc, int* __restrict__ rowptr,
                          int2* __restrict__ epk) {
    int tid = blockIdx.x * 256 + threadIdx.x;
    if (tid == 0) rowptr[0] = 0;
    if (tid < N_NODES)
        rowptr[tid + 1] = locs[tid] + bsum[tid >> 8];
    if (tid < N_TOT) {
        int src, dst;
        if (tid < N_EDGES) { src = ei[tid]; dst = ei[N_EDGES + tid]; }
        else               { src = dst = tid - N_EDGES; }
        int base = bsum[dst >> 8] + ((dst & 255) ? locs[dst - 1] : 0);
        int pos = base + atomicAdd(&fc[dst], 1);
        epk[pos] = make_int2(src, __float_as_int(dis[src] * dis[dst]));
    }
}

// ---- fused layer v2: out = act( Agg(hw) * Wt^T + bias ).
// Latency fixes vs v1 (which measured 59us @ MfmaUtil 4% / Occ 19%):
//  * block's CSR slice [rowptr[m0], rowptr[m0+64]) is CONTIGUOUS -> one
//    coalesced copy into LDS; per-node chains start from LDS broadcast
//    (~60cy) instead of a dependent global epk load (~500cy); no shuffles.
//  * B (weights, 131KB, L2-hot, shared by all 782 blocks) read directly
//    from global as MFMA fragments -> no lB buffer, ZERO mid-GEMM barriers.
//  * LDS 48KB -> ~40KB, __launch_bounds__(256,4): 4 blocks/CU.
__global__ __launch_bounds__(256, 4) void layer_kernel(
        const unsigned short* __restrict__ hw,    // gather table [N][D] bf16
        const int* __restrict__ rowptr,
        const int2* __restrict__ epk,
        const unsigned short* __restrict__ Bt,    // Wt [n][k] bf16
        const float* __restrict__ bias,
        unsigned short* __restrict__ out_bf,
        float* __restrict__ out_f32,
        int mode) {                               // 1 = relu->bf16, 0 = f32
    __shared__ unsigned short lA[BLKM * D];       // 32 KB
    __shared__ int2 eL[EMAX];                     // 7 KB
    __shared__ int rL[BLKM + 1];                  // 260 B
    int t = threadIdx.x;
    int bid = blockIdx.x;
    int wid = t >> 6, lane = t & 63;
    int h = lane >> 5, hl = lane & 31;
    int hw8 = wid * 2 + h;                        // half-wave id 0..7
    int m0 = bid * BLKM;
    int mEnd = m0 + BLKM; if (mEnd > N_NODES) mEnd = N_NODES;

    // ---- prologue: stage rowptr slice + edge slice into LDS ----
    int s0b = rowptr[m0];                         // uniform (broadcast load)
    int s1b = rowptr[mEnd];
    int nE = s1b - s0b;
    bool useL = (nE <= EMAX);                     // block-uniform
    if (t <= BLKM) {
        int idx = m0 + t;
        rL[t] = rowptr[idx > N_NODES ? N_NODES : idx];
    }
    if (useL)
        for (int i = t; i < nE; i += 256) eL[i] = epk[s0b + i];
    __syncthreads();

    // ---- agg phase: 8 nodes per half-wave, 8 row-gathers in flight ----
    for (int j = 0; j < 8; ++j) {
        int nn = hw8 * 8 + j;
        int s0 = rL[nn], s1 = rL[nn + 1];
        int deg = s1 - s0;
        int ls0 = s0 - s0b;
        float acc[8] = {};
        for (int off = 0; off < deg; off += 8) {
            int se[8]; float ne[8];
            #pragma unroll
            for (int e = 0; e < 8; ++e) {
                int idx = off + e;
                int2 ep = make_int2(0, 0);
                if (idx < deg) ep = useL ? eL[ls0 + idx] : epk[s0 + idx];
                se[e] = ep.x; ne[e] = __int_as_float(ep.y);
            }
            u16x8 rw[8];
            #pragma unroll
            for (int e = 0; e < 8; ++e)
                rw[e] = *(const u16x8*)(hw + (size_t)se[e] * D + hl * 8);
            #pragma unroll
            for (int e = 0; e < 8; ++e)
                #pragma unroll
                for (int k = 0; k < 8; ++k) acc[k] += ne[e] * bf2f(rw[e][k]);
        }
        u16x8 o;
        #pragma unroll
        for (int k = 0; k < 8; ++k) o[k] = f2bf(acc[k]);
        int chunk = (hl & ~7) | ((hl ^ nn) & 7);      // A chunk swizzle (write)
        *(u16x8*)(lA + nn * D + chunk * 8) = o;
    }

    __syncthreads();   // A-tile ready

    // ---- GEMM phase: 64(M) x 64(N-quarter) per wave; B direct from global ----
    int q = lane >> 4, r = lane & 15;
    int noff = wid * 64;
    const unsigned short* Bw = Bt + (size_t)(noff + r) * D + q * 8;
    f32x4 acc4[4][4] = {};
    #pragma unroll 1
    for (int st = 0; st < 8; ++st) {
        bf16x8 af[4], bfr[4];
        #pragma unroll
        for (int nt = 0; nt < 4; ++nt)
            bfr[nt] = *(const bf16x8*)(Bw + (size_t)(nt * 16) * D + st * 32);
        #pragma unroll
        for (int mt = 0; mt < 4; ++mt) {
            int row = mt * 16 + r;
            int ch = st * 4 + q;
            int chs = (ch & ~7) | ((ch ^ row) & 7);   // A chunk swizzle (read)
            af[mt] = *(const bf16x8*)(lA + row * D + chs * 8);
        }
        #pragma unroll
        for (int mt = 0; mt < 4; ++mt)
            #pragma unroll
            for (int nt = 0; nt < 4; ++nt)
                acc4[mt][nt] = __builtin_amdgcn_mfma_f32_16x16x32_bf16(
                    bfr[nt], af[mt], acc4[mt][nt], 0, 0, 0);
    }

    // ---- epilogue: bias (+relu), swapped-operand layout: row=r, col=q*4+i ----
    #pragma unroll
    for (int mt = 0; mt < 4; ++mt) {
        int mrow = m0 + mt * 16 + r;
        if (mrow >= N_NODES) continue;
        #pragma unroll
        for (int nt = 0; nt < 4; ++nt) {
            int col = noff + nt * 16 + (q << 2);
            float4 bv = *(const float4*)(bias + col);
            float v[4] = { acc4[mt][nt][0] + bv.x, acc4[mt][nt][1] + bv.y,
                           acc4[mt][nt][2] + bv.z, acc4[mt][nt][3] + bv.w };
            if (mode) {
                u16x4 o;
                #pragma unroll
                for (int i = 0; i < 4; ++i) o[i] = f2bf(fmaxf(v[i], 0.f));
                *(u16x4*)(out_bf + (size_t)mrow * D + col) = o;
            } else {
                float4 o = { v[0], v[1], v[2], v[3] };
                *(float4*)(out_f32 + (size_t)mrow * D + col) = o;
            }
        }
    }
}

extern "C" void kernel_launch(void* const* d_in, const int* in_sizes, int n_in,
                              void* d_out, int out_size, void* d_ws, size_t ws_size,
                              hipStream_t stream) {
    const float* x  = (const float*)d_in[0];
    const int*   ei = (const int*)d_in[1];
    const float* We = (const float*)d_in[2];
    const float* be = (const float*)d_in[3];
    const float* W1 = (const float*)d_in[4];
    const float* b1 = (const float*)d_in[5];
    const float* W2 = (const float*)d_in[6];
    const float* b2 = (const float*)d_in[7];
    float* out = (float*)d_out;

    char* w = (char*)d_ws;
    auto alloc = [&](size_t bytes) {
        char* p = w;
        w += (bytes + 255) & ~(size_t)255;
        return p;
    };
    // cnt, fc, done contiguous -> single memset covers all three
    int*            cnt    = (int*)alloc((size_t)N_NODES * 4);
    int*            fc     = (int*)alloc((size_t)N_NODES * 4);
    int*            done   = (int*)alloc(4);
    size_t zero_span = (size_t)((char*)(done + 64) - (char*)cnt);
    int*            rowptr = (int*)alloc((size_t)(N_NODES + 1) * 4);
    int*            locs   = (int*)alloc((size_t)N_NODES * 4);
    int*            bsum   = (int*)alloc((size_t)SCAN_B * 4);
    float*          dis    = (float*)alloc((size_t)N_NODES * 4);
    int2*           epk    = (int2*)alloc((size_t)N_TOT * 8);
    unsigned short* Wt1    = (unsigned short*)alloc((size_t)D * D * 2);
    unsigned short* Wt2    = (unsigned short*)alloc((size_t)D * D * 2);
    unsigned short* hA     = (unsigned short*)alloc((size_t)MPAD * D * 2);
    unsigned short* h1     = (unsigned short*)alloc((size_t)MPAD * D * 2);

    hipMemsetAsync(cnt, 0, zero_span, stream);
    k1_kernel<<<MPAD / 8, 256, 0, stream>>>(x, ei, We, be, W1, W2, cnt, Wt1, Wt2, hA);
    k2_kernel<<<SCAN_B, 256, 0, stream>>>(cnt, dis, locs, bsum, done);
    k3_kernel<<<(N_TOT + 255) / 256, 256, 0, stream>>>(ei, locs, bsum, dis, fc,
                                                       rowptr, epk);
    // layer 1: h1 = relu( Agg(hA) * W1 + b1 )
    layer_kernel<<<LGRID, 256, 0, stream>>>(hA, rowptr, epk, Wt1, b1,
                                            h1, nullptr, 1);
    // layer 2: out = Agg(h1) * W2 + b2
    layer_kernel<<<LGRID, 256, 0, stream>>>(h1, rowptr, epk, Wt2, b2,
                                            nullptr, out, 0);
}